// Round 10
// baseline (548.883 us; speedup 1.0000x reference)
//
#include <hip/hip_runtime.h>

#define S_LEN 1024
#define BATCH 4096
#define NIN 64
#define NHID 128
#define BT 16      // batch rows per block (one h-chain per block)

typedef __attribute__((ext_vector_type(8))) short bf16x8;
typedef __attribute__((ext_vector_type(4))) float f32x4;

__device__ __forceinline__ unsigned cvt_pk(float lo, float hi) {
    unsigned r;
    asm("v_cvt_pk_bf16_f32 %0, %1, %2" : "=v"(r) : "v"(lo), "v"(hi));
    return r;
}
__device__ __forceinline__ float tanh_fast(float z) {
    // tanh(z) = 1 - 2/(e^{2z}+1)
    float u = __builtin_amdgcn_exp2f(z * 2.885390081777927f);
    return fmaf(-2.0f, __builtin_amdgcn_rcpf(u + 1.0f), 1.0f);
}
// barrier without vmcnt drain (x prefetch loads stay in flight)
__device__ __forceinline__ void lds_barrier() {
    asm volatile("s_waitcnt lgkmcnt(0)\n\ts_barrier" ::: "memory");
    __builtin_amdgcn_sched_barrier(0);
}

#define MFMA __builtin_amdgcn_mfma_f32_16x16x32_bf16

__device__ __forceinline__ bf16x8 pack8(const f32x4& a, const f32x4& b) {
    union { bf16x8 v; unsigned u[4]; } r;
    r.u[0] = cvt_pk(a[0], a[1]); r.u[1] = cvt_pk(a[2], a[3]);
    r.u[2] = cvt_pk(b[0], b[1]); r.u[3] = cvt_pk(b[2], b[3]);
    return r.v;
}

// k-split scheme: wave w owns n-range AND k-slice [32w, 32w+32).
// Permuted-k (verified R6-R9): B-slot (kg,j) of k-tile w carries logical
// hidden m = 32w + 4kg + (j&3) + 16*(j>>2) => B-frag = same-lane cvt_pk of
// the wave's own tanh'd outputs (v0,v1). W_hh loaded column-permuted.
// Exchange carries f32 PARTIALS (W_hh[partner n]·h_slice), not h: 8
// independent MFMAs per step (no dependent chain).
// LDS: 2 bufs x [owner(4)][writer(4)][T(2)] x lane*16B = 64 KB.

__global__ __launch_bounds__(256, 1)
void rnn_kernel(const float* __restrict__ x,
                const float* __restrict__ W_ih,
                const float* __restrict__ b_ih,
                const float* __restrict__ W_hh,
                const float* __restrict__ b_hh,
                float* __restrict__ out)
{
    __shared__ __align__(16) char lds[65536];
    const int tid  = threadIdx.x;
    const int wv   = tid >> 6;        // 0..3 — one wave per SIMD, uniform code
    const int lane = tid & 63;
    const int col  = lane & 15;
    const int kg   = lane >> 4;
    const int bb0  = blockIdx.x * BT;

    // zero both exchange buffers (h(0) = 0 -> zero partials)
    for (int i = tid; i < 16384; i += 256) ((int*)lds)[i] = 0;

    const int OWN = wv;               // runtime-uniform; addresses only
    const int o1 = (OWN + 1) & 3, o2 = (OWN + 2) & 3, o3 = (OWN + 3) & 3;
    char* lbx = lds + (lane << 4);
    // chunk (o, w, T) at ((o*8 + w*2 + T) << 10) + lane*16 ; buf at +32KB
    char* w10 = lbx + ((o1 * 8 + OWN * 2 + 0) << 10);
    char* w11 = lbx + ((o1 * 8 + OWN * 2 + 1) << 10);
    char* w20 = lbx + ((o2 * 8 + OWN * 2 + 0) << 10);
    char* w21 = lbx + ((o2 * 8 + OWN * 2 + 1) << 10);
    char* w30 = lbx + ((o3 * 8 + OWN * 2 + 0) << 10);
    char* w31 = lbx + ((o3 * 8 + OWN * 2 + 1) << 10);
    const char* r10 = lbx + ((OWN * 8 + o1 * 2 + 0) << 10);
    const char* r11 = lbx + ((OWN * 8 + o1 * 2 + 1) << 10);
    const char* r20 = lbx + ((OWN * 8 + o2 * 2 + 0) << 10);
    const char* r21 = lbx + ((OWN * 8 + o2 * 2 + 1) << 10);
    const char* r30 = lbx + ((OWN * 8 + o3 * 2 + 0) << 10);
    const char* r31 = lbx + ((OWN * 8 + o3 * 2 + 1) << 10);

    // ---- persistent weights
    auto loadWhh = [&](int nt) -> bf16x8 {   // A-frag, k-tile OWN, permuted cols
        const float* pw = W_hh + (size_t)(16 * nt + col) * NHID + 32 * OWN + 4 * kg;
        f32x4 c0 = *(const f32x4*)(pw);        // j = 0..3
        f32x4 c1 = *(const f32x4*)(pw + 16);   // j = 4..7
        return pack8(c0, c1);
    };
    bf16x8 whhP10 = loadWhh(2 * o1),  whhP11 = loadWhh(2 * o1 + 1);
    bf16x8 whhP20 = loadWhh(2 * o2),  whhP21 = loadWhh(2 * o2 + 1);
    bf16x8 whhP30 = loadWhh(2 * o3),  whhP31 = loadWhh(2 * o3 + 1);
    bf16x8 whhO0  = loadWhh(2 * OWN), whhO1  = loadWhh(2 * OWN + 1);

    const int tt0 = 2 * OWN, tt1 = tt0 + 1;
    bf16x8 wihA0, wihB0, wihA1, wihB1;       // natural k (x side unpermuted)
    {
        const float* q0 = W_ih + (size_t)(16 * tt0 + col) * NIN + 8 * kg;
        const float* q1 = W_ih + (size_t)(16 * tt1 + col) * NIN + 8 * kg;
        wihA0 = pack8(*(const f32x4*)(q0),      *(const f32x4*)(q0 + 4));
        wihB0 = pack8(*(const f32x4*)(q0 + 32), *(const f32x4*)(q0 + 36));
        wihA1 = pack8(*(const f32x4*)(q1),      *(const f32x4*)(q1 + 4));
        wihB1 = pack8(*(const f32x4*)(q1 + 32), *(const f32x4*)(q1 + 36));
    }
    f32x4 bias0, bias1;
    {
        f32x4 bi = *(const f32x4*)(b_ih + 16 * tt0 + 4 * kg);
        f32x4 bh = *(const f32x4*)(b_hh + 16 * tt0 + 4 * kg);
        bias0 = bi + bh;
        bi = *(const f32x4*)(b_ih + 16 * tt1 + 4 * kg);
        bh = *(const f32x4*)(b_hh + 16 * tt1 + 4 * kg);
        bias1 = bi + bh;
    }

    const float* xlane = x + ((size_t)bb0 + col) * NIN + kg * 8;
    auto loadStage = [&](f32x4& v0, f32x4& v1, f32x4& v2, f32x4& v3, int t) {
        if (t < S_LEN) {
            const float* p = xlane + (size_t)t * (BATCH * NIN);
            v0 = *(const f32x4*)(p);      v1 = *(const f32x4*)(p + 4);
            v2 = *(const f32x4*)(p + 32); v3 = *(const f32x4*)(p + 36);
        }
    };
    // xp for own 2 n-tiles from packed x frags (4 MFMAs, off-critical)
    auto computeXP = [&](const bf16x8& xa, const bf16x8& xb,
                         f32x4& q0, f32x4& q1) {
        f32x4 p0 = bias0, p1 = bias1;
        p0 = MFMA(wihA0, xa, p0, 0, 0, 0);
        p1 = MFMA(wihA1, xa, p1, 0, 0, 0);
        p0 = MFMA(wihB0, xb, p0, 0, 0, 0);
        p1 = MFMA(wihB1, xb, p1, 0, 0, 0);
        q0 = p0; q1 = p1;
    };

    // ---- prologue
    f32x4 A0, A1, A2, A3, B0, B1, B2, B3;     // two raw x banks
    bf16x8 PCa, PCb, PNa, PNb;                // packed x double-buffer
    f32x4 pO0, pO1;                           // own partials (incl. xp)
    loadStage(A0, A1, A2, A3, 0);
    PCa = pack8(A0, A1); PCb = pack8(A2, A3);
    computeXP(PCa, PCb, pO0, pO1);            // pO = xp(0) (+ W·h(0)=0)
    loadStage(A0, A1, A2, A3, 1);
    PCa = pack8(A0, A1); PCb = pack8(A2, A3); // PC = x(1) for step 0
    loadStage(A0, A1, A2, A3, 2);             // packed at step 0
    loadStage(B0, B1, B2, B3, 3);             // packed at step 1
    __syncthreads();                          // LDS zeros visible

    auto cstep = [&](int t, f32x4& s0, f32x4& s1, f32x4& s2, f32x4& s3,
                     const bf16x8& pca, const bf16x8& pcb,
                     bf16x8& pna, bf16x8& pnb, bool last) {
        const int rb = (t & 1) << 15;
        // 1. partner partial reads (latency covered by xp below)
        f32x4 q10 = *(const f32x4*)(r10 + rb);
        f32x4 q11 = *(const f32x4*)(r11 + rb);
        f32x4 q20 = *(const f32x4*)(r20 + rb);
        f32x4 q21 = *(const f32x4*)(r21 + rb);
        f32x4 q30 = *(const f32x4*)(r30 + rb);
        f32x4 q31 = *(const f32x4*)(r31 + rb);
        // 2. xp(t+1) — independent issue
        f32x4 xq0, xq1;
        if (t + 1 < S_LEN) computeXP(pca, pcb, xq0, xq1);
        // 3. sum partials + tanh -> h(t+1) slice
        f32x4 pre0 = (pO0 + q10) + (q20 + q30);
        f32x4 pre1 = (pO1 + q11) + (q21 + q31);
        f32x4 v0, v1;
        #pragma unroll
        for (int i = 0; i < 4; ++i) v0[i] = tanh_fast(pre0[i]);
        #pragma unroll
        for (int i = 0; i < 4; ++i) v1[i] = tanh_fast(pre1[i]);

        if (last) {
            float* ob = out + ((size_t)bb0 + col) * NHID + 32 * OWN + 4 * kg;
            *(f32x4*)(ob)      = v0;
            *(f32x4*)(ob + 16) = v1;
            lds_barrier();
            return;
        }
        // 4. own B-frag (same-lane pack, permuted-k)
        bf16x8 Bo;
        {
            union { bf16x8 v; unsigned u[4]; } fb;
            fb.u[0] = cvt_pk(v0[0], v0[1]); fb.u[1] = cvt_pk(v0[2], v0[3]);
            fb.u[2] = cvt_pk(v1[0], v1[1]); fb.u[3] = cvt_pk(v1[2], v1[3]);
            Bo = fb.v;
        }
        // 5. partner partials for h(t+2): 6 INDEPENDENT MFMAs, write out
        const int nb = ((t + 1) & 1) << 15;
        const f32x4 z4 = {0.f, 0.f, 0.f, 0.f};
        f32x4 g10 = MFMA(whhP10, Bo, z4, 0, 0, 0);
        f32x4 g11 = MFMA(whhP11, Bo, z4, 0, 0, 0);
        f32x4 g20 = MFMA(whhP20, Bo, z4, 0, 0, 0);
        f32x4 g21 = MFMA(whhP21, Bo, z4, 0, 0, 0);
        f32x4 g30 = MFMA(whhP30, Bo, z4, 0, 0, 0);
        f32x4 g31 = MFMA(whhP31, Bo, z4, 0, 0, 0);
        *(f32x4*)(w10 + nb) = g10;
        *(f32x4*)(w11 + nb) = g11;
        *(f32x4*)(w20 + nb) = g20;
        *(f32x4*)(w21 + nb) = g21;
        *(f32x4*)(w30 + nb) = g30;
        *(f32x4*)(w31 + nb) = g31;
        // 6. own partials issued LAST — latency crosses the barrier
        pO0 = MFMA(whhO0, Bo, xq0, 0, 0, 0);
        pO1 = MFMA(whhO1, Bo, xq1, 0, 0, 0);
        // 7. x pipeline: pack x(t+2), refill bank with x(t+4)
        if (t + 2 < S_LEN) { pna = pack8(s0, s1); pnb = pack8(s2, s3); }
        loadStage(s0, s1, s2, s3, t + 4);
        lds_barrier();
    };

    for (int m = 0; m < 511; ++m) {
        const int t = 2 * m;
        cstep(t,     A0, A1, A2, A3, PCa, PCb, PNa, PNb, false);
        cstep(t + 1, B0, B1, B2, B3, PNa, PNb, PCa, PCb, false);
    }
    cstep(1022, A0, A1, A2, A3, PCa, PCb, PNa, PNb, false);
    cstep(1023, B0, B1, B2, B3, PNa, PNb, PCa, PCb, true);
}

extern "C" void kernel_launch(void* const* d_in, const int* in_sizes, int n_in,
                              void* d_out, int out_size, void* d_ws, size_t ws_size,
                              hipStream_t stream) {
    const float* x    = (const float*)d_in[0];
    const float* W_ih = (const float*)d_in[1];
    const float* b_ih = (const float*)d_in[2];
    const float* W_hh = (const float*)d_in[3];
    const float* b_hh = (const float*)d_in[4];
    float* out = (float*)d_out;

    dim3 grid(BATCH / BT);
    dim3 block(256);
    rnn_kernel<<<grid, block, 0, stream>>>(x, W_ih, b_ih, W_hh, b_hh, out);
}